// Round 3
// baseline (526.498 us; speedup 1.0000x reference)
//
#include <hip/hip_runtime.h>

#define NE 8
#define HW 128
#define OUT_HW 384
#define C1 64
#define C2 32
#define C3 9

typedef __attribute__((ext_vector_type(4))) float f32x4;
typedef __attribute__((ext_vector_type(8))) short bf16x8s;

// Prepacked conv2 weights, bf16: [e][koff(ky*3+kx)][oc=32][ic=64]
__device__ __align__(16) unsigned short g_w2b[NE * 9 * C2 * C1];
// Prepacked conv3 weights, bf16: [e][koff][oc=16 (9 valid)][ic=32]
__device__ __align__(16) unsigned short g_w3b[NE * 9 * 16 * 32];

__device__ __forceinline__ unsigned short f2bf(float f) {
    unsigned u = __builtin_bit_cast(unsigned, f);
    u += 0x7fffu + ((u >> 16) & 1u);          // round-nearest-even
    return (unsigned short)(u >> 16);
}

__global__ void repack_weights_kernel(const float* __restrict__ w2,
                                      const float* __restrict__ w3) {
    int i = blockIdx.x * 256 + threadIdx.x;
    const int n2 = NE * C2 * C1 * 9;          // 36864
    const int n3 = NE * 9 * 16 * 32;          // 36864
    if (i < n2) {
        // source: [e][oc][ic][ky][kx] -> dest [e][koff][oc][ic]
        int e = i / (C2 * C1 * 9);
        int r = i - e * (C2 * C1 * 9);
        int oc = r / (C1 * 9); r -= oc * (C1 * 9);
        int ic = r / 9;
        int koff = r - ic * 9;
        g_w2b[((e * 9 + koff) * C2 + oc) * C1 + ic] = f2bf(w2[i]);
    } else if (i < n2 + n3) {
        int j = i - n2;
        int e = j / (9 * 16 * 32);
        int r = j - e * (9 * 16 * 32);
        int koff = r / 512; r -= koff * 512;
        int oc = r / 32;
        int ic = r - oc * 32;
        float v = 0.f;
        if (oc < C3) v = w3[((e * C3 + oc) * 32 + ic) * 9 + koff];
        g_w3b[((e * 9 + koff) * 16 + oc) * 32 + ic] = f2bf(v);
    }
}

__device__ __forceinline__ float fast_tanh(float x) {
    float ax = fabsf(x);
    float ex = __expf(2.0f * ax);                       // inf-safe
    float tv = 1.0f - 2.0f * __builtin_amdgcn_rcpf(ex + 1.0f);
    return copysignf(tv, x);
}

__launch_bounds__(256, 6)
__global__ void espcn_fused_kernel(const float* __restrict__ x,
                                   const int* __restrict__ ci,
                                   const float* __restrict__ w1,
                                   const float* __restrict__ b1,
                                   const float* __restrict__ b2,
                                   const float* __restrict__ b3,
                                   float* __restrict__ out) {
    __shared__ float xs[16][17];                            // x patch
    __shared__ __align__(16) unsigned short h1s[144 * 64];  // [pixel][ic] bf16, XOR-swizzled (128B rows)
    __shared__ __align__(16) unsigned short h2b[100 * 32];  // [pixel][ic] bf16, XOR-swizzled (64B rows)

    const int tx = blockIdx.x, ty = blockIdx.y, b = blockIdx.z;
    const int R0 = ty * 8, C0 = tx * 8;
    int e = ci[b];
    e = __builtin_amdgcn_readfirstlane(e);                  // force SGPR: scalar weight loads
    const int t = threadIdx.x;
    const int lane = t & 63, wave = t >> 6;

    // ---- phase 0: stage x patch rows [R0-4, R0+12), cols [C0-4, C0+12) ----
    {
        int i = t >> 4, j = t & 15;
        int gy = R0 - 4 + i, gx = C0 - 4 + j;
        float v = 0.f;
        if (gy >= 0 && gy < HW && gx >= 0 && gx < HW)
            v = x[(b * HW + gy) * HW + gx];
        xs[i][j] = v;
    }
    __syncthreads();

    // ---- phase 1: conv1 (5x5, 1->64) + tanh -> h1s[pixel][ic] bf16 ----
    // 768 tasks = 64 channels x 12 columns; 3 tasks per thread.
    {
        const float* w1e = w1 + e * C1 * 25;
        const float* b1e = b1 + e * C1;
        #pragma unroll
        for (int it = 0; it < 3; ++it) {
            int task = it * 256 + t;
            int c = task / 12, j = task - c * 12;
            float wreg[25];
            #pragma unroll
            for (int q = 0; q < 25; ++q) wreg[q] = w1e[c * 25 + q];
            float bias = b1e[c];
            float acc[12];
            #pragma unroll
            for (int r = 0; r < 12; ++r) acc[r] = bias;
            #pragma unroll
            for (int i = 0; i < 16; ++i) {
                float v0 = xs[i][j], v1 = xs[i][j + 1], v2 = xs[i][j + 2],
                      v3 = xs[i][j + 3], v4 = xs[i][j + 4];
                #pragma unroll
                for (int dy = 0; dy < 5; ++dy) {
                    int r = i - dy;
                    if (r >= 0 && r < 12) {
                        acc[r] = fmaf(v0, wreg[dy * 5 + 0], acc[r]);
                        acc[r] = fmaf(v1, wreg[dy * 5 + 1], acc[r]);
                        acc[r] = fmaf(v2, wreg[dy * 5 + 2], acc[r]);
                        acc[r] = fmaf(v3, wreg[dy * 5 + 3], acc[r]);
                        acc[r] = fmaf(v4, wreg[dy * 5 + 4], acc[r]);
                    }
                }
            }
            #pragma unroll
            for (int r = 0; r < 12; ++r) {
                int gy = R0 - 2 + r, gx = C0 - 2 + j;
                float val = (gy >= 0 && gy < HW && gx >= 0 && gx < HW) ? fast_tanh(acc[r]) : 0.f;
                int p = r * 12 + j;
                int off = ((p << 7) + (c << 1)) ^ ((p & 7) << 4);
                *(unsigned short*)((char*)h1s + off) = f2bf(val);
            }
        }
    }
    __syncthreads();

    // ---- phase 2: conv2 (3x3, 64->32) as bf16 MFMA + tanh -> h2b bf16 ----
    // M = 100 pixels (8 tiles of 16, padded), N = 32 oc (2 tiles), K = 576 (18 steps of 32).
    {
        const unsigned short* w2e = g_w2b + e * 9 * C2 * C1;
        const int g = lane >> 4, r16 = lane & 15;
        int ps0 = wave * 32 + r16;       if (ps0 > 99) ps0 = 99;
        int ps1 = wave * 32 + 16 + r16;  if (ps1 > 99) ps1 = 99;
        const int ab0 = (ps0 / 10) * 12 + (ps0 % 10);
        const int ab1 = (ps1 / 10) * 12 + (ps1 % 10);
        f32x4 acc00 = {0.f, 0.f, 0.f, 0.f}, acc01 = {0.f, 0.f, 0.f, 0.f};
        f32x4 acc10 = {0.f, 0.f, 0.f, 0.f}, acc11 = {0.f, 0.f, 0.f, 0.f};
        const int laneB = (r16 * C1 + g * 8);          // elements
        #pragma unroll
        for (int s = 0; s < 18; ++s) {
            const int koff = s >> 1;
            const int drow = (koff / 3) * 12 + (koff % 3);
            const int icoff2 = ((s & 1) * 32 + g * 8) * 2;
            int r0 = ab0 + drow, r1 = ab1 + drow;
            int o0 = ((r0 << 7) + icoff2) ^ ((r0 & 7) << 4);
            int o1 = ((r1 << 7) + icoff2) ^ ((r1 & 7) << 4);
            bf16x8s A0 = *(const bf16x8s*)((const char*)h1s + o0);
            bf16x8s A1 = *(const bf16x8s*)((const char*)h1s + o1);
            const unsigned short* wp = w2e + koff * C2 * C1 + (s & 1) * 32;
            bf16x8s B0 = *(const bf16x8s*)(wp + laneB);
            bf16x8s B1 = *(const bf16x8s*)(wp + 16 * C1 + laneB);
            acc00 = __builtin_amdgcn_mfma_f32_16x16x32_bf16(A0, B0, acc00, 0, 0, 0);
            acc01 = __builtin_amdgcn_mfma_f32_16x16x32_bf16(A0, B1, acc01, 0, 0, 0);
            acc10 = __builtin_amdgcn_mfma_f32_16x16x32_bf16(A1, B0, acc10, 0, 0, 0);
            acc11 = __builtin_amdgcn_mfma_f32_16x16x32_bf16(A1, B1, acc11, 0, 0, 0);
        }
        // epilogue: D row = (lane>>4)*4 + reg (pixel), col = lane&15 (oc)
        const float* b2e = b2 + e * C2;
        float bias0 = b2e[r16], bias1 = b2e[16 + r16];
        #pragma unroll
        for (int m = 0; m < 2; ++m) {
            f32x4 aN0 = m ? acc10 : acc00;
            f32x4 aN1 = m ? acc11 : acc01;
            int mtbase = wave * 32 + m * 16;
            #pragma unroll
            for (int q = 0; q < 4; ++q) {
                int pd = mtbase + g * 4 + q;
                if (pd < 100) {
                    int y = pd / 10, xq2 = pd - y * 10;
                    int gy = R0 - 1 + y, gx = C0 - 1 + xq2;
                    bool inimg = (gy >= 0 && gy < HW && gx >= 0 && gx < HW);
                    float v0 = inimg ? fast_tanh(aN0[q] + bias0) : 0.f;
                    float v1 = inimg ? fast_tanh(aN1[q] + bias1) : 0.f;
                    int swz = (pd & 3) << 4;
                    int off0 = (pd << 6) + ((2 * r16) ^ swz);
                    int off1 = (pd << 6) + ((2 * r16 + 32) ^ swz);
                    *(unsigned short*)((char*)h2b + off0) = f2bf(v0);
                    *(unsigned short*)((char*)h2b + off1) = f2bf(v1);
                }
            }
        }
    }
    __syncthreads();

    // ---- phase 3: conv3 (3x3, 32->9 pad 16) as bf16 MFMA + pixel shuffle ----
    // M = 64 output pixels (4 tiles, one per wave), N = 16 (9 valid), K = 288 (9 steps).
    {
        const unsigned short* w3e = g_w3b + e * 9 * 16 * 32;
        const int g = lane >> 4, r16 = lane & 15;
        const int pxA = wave * 16 + r16;            // A-row pixel
        const int oyA = pxA >> 3, oxA = pxA & 7;
        f32x4 acc = {0.f, 0.f, 0.f, 0.f};
        #pragma unroll
        for (int s = 0; s < 9; ++s) {
            const int ky = s / 3, kx = s % 3;
            int p = (oyA + ky) * 10 + (oxA + kx);
            int offA = (p << 6) + ((g * 16) ^ ((p & 3) << 4));
            bf16x8s A = *(const bf16x8s*)((const char*)h2b + offA);
            bf16x8s B = *(const bf16x8s*)(w3e + (s * 16 + r16) * 32 + g * 8);
            acc = __builtin_amdgcn_mfma_f32_16x16x32_bf16(A, B, acc, 0, 0, 0);
        }
        // D: row (pixel-in-tile) = g*4+q, col (oc) = r16
        if (r16 < C3) {
            float bias = b3[e * C3 + r16];
            #pragma unroll
            for (int q = 0; q < 4; ++q) {
                int pxd = wave * 16 + g * 4 + q;
                int oyd = pxd >> 3, oxd = pxd & 7;
                int gr = (R0 + oyd) * 3 + r16 / 3;
                int gc = (C0 + oxd) * 3 + r16 % 3;
                out[(b * OUT_HW + gr) * OUT_HW + gc] = acc[q] + bias;
            }
        }
    }
}

extern "C" void kernel_launch(void* const* d_in, const int* in_sizes, int n_in,
                              void* d_out, int out_size, void* d_ws, size_t ws_size,
                              hipStream_t stream) {
    const float* x  = (const float*)d_in[0];
    const int*   ci = (const int*)  d_in[1];
    const float* w1 = (const float*)d_in[2];
    const float* b1 = (const float*)d_in[3];
    const float* w2 = (const float*)d_in[4];
    const float* b2 = (const float*)d_in[5];
    const float* w3 = (const float*)d_in[6];
    const float* b3 = (const float*)d_in[7];
    float* out = (float*)d_out;

    {
        const int total = NE * C2 * C1 * 9 + NE * 9 * 16 * 32;
        repack_weights_kernel<<<(total + 255) / 256, 256, 0, stream>>>(w2, w3);
    }
    {
        dim3 grid(HW / 8, HW / 8, 32);
        espcn_fused_kernel<<<grid, 256, 0, stream>>>(x, ci, w1, b1, b2, b3, out);
    }
}